// Round 3
// baseline (3726.348 us; speedup 1.0000x reference)
//
#include <hip/hip_runtime.h>

// LSTM T=256, N=128, D=H=1024, L=2.  Persistent cooperative kernel, 256 WGs x 512.
// WG (layer l, slice s) owns hidden units [8s,8s+8) => 32 gate cols, weights in LDS.
// Round-7 changes vs round-6 (evidence: VGPR 116 => RA rotated a small register
// window across the batched loads; WAW reuse of VMEM dst regs inserts serial
// waitcnts, capping MLP at ~8; plus 32K threads polling agent loads every ~600cy
// is an LLC request storm):
//  (1) keep-alive asm (16 x "v" inputs) after each 16-load batch forces ALL
//      fragments into distinct live registers -> compiler emits one counted
//      vmcnt per batch, 32 loads in flight.  Layer-1 pipelines 4 batches
//      (P0,P1,Q0,Q1) so Q loads fly under P MFMAs.
//  (2) dense 4-B flags; ONE wave polls (lane i checks 2 flags per 8-B agent
//      load), s_sleep(3) backoff.  ~6x less poll traffic.
// h exchange unchanged: s-major slots (contiguous 2KB/WG producer stores),
// time-unique slot addresses, agent stores staged via LDS, plain cached
// consumer loads.  c-state in registers.  glds stride 36.

typedef _Float16 f16;
typedef f16  v8f16 __attribute__((ext_vector_type(8)));
typedef float v4f32 __attribute__((ext_vector_type(4)));

#define TSTEPS 256
#define SLOT   131072u
static constexpr size_t HS_BANK = (size_t)258 * SLOT;   // elems per layer bank

#define SZ_W     ((size_t)2*4096*2048*2)   /* fp16 weights [l][col][k2048] */
#define SZ_B     ((size_t)2*4096*4)        /* fused bias fp32 */
#define SZ_HSEQ  ((size_t)2*258*SLOT*2)    /* h slots, 2 banks, fp16 */
#define SZ_BAR   ((size_t)4096)            /* dense flags: f0=bar[0..127], f1=bar[128..255] */
#define SZ_XF    ((size_t)256*128*1024*2)  /* x in fp16 */
#define NEED1    (SZ_W + SZ_B + SZ_HSEQ + SZ_BAR)
#define NEED2    (NEED1 + SZ_XF)

__global__ void lstm_init(const float* __restrict__ x,
                          const float* __restrict__ h0,
                          const float* __restrict__ Wih, const float* __restrict__ Whh,
                          const float* __restrict__ bih, const float* __restrict__ bhh,
                          f16* __restrict__ wsW, float* __restrict__ wsB,
                          f16* __restrict__ hseq, unsigned* __restrict__ bar,
                          f16* __restrict__ xf, int do_xf)
{
    size_t tid  = (size_t)blockIdx.x * blockDim.x + threadIdx.x;
    size_t nthr = (size_t)gridDim.x * blockDim.x;
    // weights: [l][col][k], k<1024 -> W_ih, k>=1024 -> W_hh
    for (size_t i = tid; i < 16777216u; i += nthr) {
        unsigned l = (unsigned)(i >> 23), rem = (unsigned)(i & 8388607u);
        unsigned col = rem >> 11, k = rem & 2047u;
        float v = (k < 1024u) ? Wih[(size_t)l*4194304u + (size_t)col*1024u + k]
                              : Whh[(size_t)l*4194304u + (size_t)col*1024u + (k-1024u)];
        wsW[i] = (f16)v;
    }
    for (size_t i = tid; i < 8192u; i += nthr) wsB[i] = bih[i] + bhh[i];
    // initial h slots in s-major layout: (n,k) -> (k>>3)*1024 + n*8 + (k&7)
    for (size_t i = tid; i < 131072u; i += nthr) {
        unsigned n = (unsigned)(i >> 10), k = (unsigned)(i & 1023u);
        unsigned dst = ((k >> 3) << 10) + (n << 3) + (k & 7u);
        hseq[dst]           = (f16)h0[i];             // layer0 slot 0
        hseq[HS_BANK + dst] = (f16)h0[131072u + i];   // layer1 slot 0
    }
    for (size_t i = tid; i < 1024u; i += nthr) bar[i] = 0u;   // all flags
    if (do_xf) {
        for (size_t i = tid; i < 33554432u; i += nthr) xf[i] = (f16)x[i];
    }
}

__device__ __forceinline__ float sigmoid_fast(float v) { return 1.0f / (1.0f + __expf(-v)); }
__device__ __forceinline__ float tanh_fast(float v)    { return 1.0f - 2.0f / (__expf(2.0f*v) + 1.0f); }

__device__ __forceinline__ v8f16 cvt8(v4f32 lo, v4f32 hi) {
    v8f16 r;
    r[0]=(f16)lo[0]; r[1]=(f16)lo[1]; r[2]=(f16)lo[2]; r[3]=(f16)lo[3];
    r[4]=(f16)hi[0]; r[5]=(f16)hi[1]; r[6]=(f16)hi[2]; r[7]=(f16)hi[3];
    return r;
}

__device__ __forceinline__ unsigned long long ld_pair(const unsigned long long* p) {
    return __hip_atomic_load(p, __ATOMIC_RELAXED, __HIP_MEMORY_SCOPE_AGENT);
}

#define CHUNK 8

// keep-alive: force all 16 fragments of a batch into distinct live registers.
// The compiler's waitcnt pass then emits one counted vmcnt for the whole batch.
#define KA16(a0, a1) asm volatile("" :: \
    "v"(a0[0]),"v"(a0[1]),"v"(a0[2]),"v"(a0[3]),"v"(a0[4]),"v"(a0[5]),"v"(a0[6]),"v"(a0[7]), \
    "v"(a1[0]),"v"(a1[1]),"v"(a1[2]),"v"(a1[3]),"v"(a1[4]),"v"(a1[5]),"v"(a1[6]),"v"(a1[7]))

// row-major source (xf): rows stride 1024 halves, a1 = rows +16
__device__ __forceinline__ void load_row(const f16* p, int off,
                                         v8f16 a0[CHUNK], v8f16 a1[CHUNK])
{
    #pragma unroll
    for (int i = 0; i < CHUNK; ++i) {
        a0[i] = *(const v8f16*)(p + off + 32*i);
        a1[i] = *(const v8f16*)(p + off + 16384 + 32*i);
    }
}

// s-major h slot: element (n,k) at (k>>3)*1024 + n*8 + (k&7)
__device__ __forceinline__ void load_sm(const f16* p, int off,
                                        v8f16 a0[CHUNK], v8f16 a1[CHUNK])
{
    #pragma unroll
    for (int i = 0; i < CHUNK; ++i) {
        a0[i] = *(const v8f16*)(p + off + 4096*i);
        a1[i] = *(const v8f16*)(p + off + 128 + 4096*i);   // rows +16 -> +128 halves
    }
}

// consume one 8-iteration chunk (B from LDS weights)
__device__ __forceinline__ void mfma_chunk(const v8f16 a0[CHUNK], const v8f16 a1[CHUNK],
                                           const f16 (*wl)[2056], int l15, int kq, int kbase,
                                           v4f32 acc[2][2])
{
    #pragma unroll
    for (int i = 0; i < CHUNK; ++i) {
        int k = kbase + 32*i;
        v8f16 b0 = *(const v8f16*)(&wl[l15     ][k + kq]);
        v8f16 b1 = *(const v8f16*)(&wl[16 + l15][k + kq]);
        acc[0][0] = __builtin_amdgcn_mfma_f32_16x16x32_f16(a0[i], b0, acc[0][0], 0, 0, 0);
        acc[0][1] = __builtin_amdgcn_mfma_f32_16x16x32_f16(a0[i], b1, acc[0][1], 0, 0, 0);
        acc[1][0] = __builtin_amdgcn_mfma_f32_16x16x32_f16(a1[i], b0, acc[1][0], 0, 0, 0);
        acc[1][1] = __builtin_amdgcn_mfma_f32_16x16x32_f16(a1[i], b1, acc[1][1], 0, 0, 0);
    }
}

__device__ __forceinline__ void reduce_splits(v4f32 acc[2][2], float (*gl)[36],
                                              int rb, int quad, int l15, int ks)
{
    if (ks == 0) {
        #pragma unroll
        for (int mt = 0; mt < 2; ++mt) {
            int rrow = (rb << 5) + (mt << 4) + (quad << 2);
            #pragma unroll
            for (int r = 0; r < 4; ++r) {
                gl[rrow + r][l15     ] = acc[mt][0][r];
                gl[rrow + r][16 + l15] = acc[mt][1][r];
            }
        }
    }
    __syncthreads();
    if (ks == 1) {
        #pragma unroll
        for (int mt = 0; mt < 2; ++mt) {
            int rrow = (rb << 5) + (mt << 4) + (quad << 2);
            #pragma unroll
            for (int r = 0; r < 4; ++r) {
                gl[rrow + r][l15     ] += acc[mt][0][r];
                gl[rrow + r][16 + l15] += acc[mt][1][r];
            }
        }
    }
    __syncthreads();
}

__device__ __forceinline__ void cell2(const float (*gl)[36], int n1, int u,
                                      float bi, float bf, float bg, float bo,
                                      float& cr0, float& cr1, float& h0o, float& h1o)
{
    {
        float gi = gl[n1][u]      + bi;
        float gf = gl[n1][8 + u]  + bf;
        float gg = gl[n1][16 + u] + bg;
        float go = gl[n1][24 + u] + bo;
        float cn = sigmoid_fast(gf) * cr0 + sigmoid_fast(gi) * tanh_fast(gg);
        cr0 = cn;
        h0o = sigmoid_fast(go) * tanh_fast(cn);
    }
    {
        int n = n1 + 64;
        float gi = gl[n][u]      + bi;
        float gf = gl[n][8 + u]  + bf;
        float gg = gl[n][16 + u] + bg;
        float go = gl[n][24 + u] + bo;
        float cn = sigmoid_fast(gf) * cr1 + sigmoid_fast(gi) * tanh_fast(gg);
        cr1 = cn;
        h1o = sigmoid_fast(go) * tanh_fast(cn);
    }
}

// stage hv in LDS, then 128 threads store the WG's CONTIGUOUS 2 KB region:
// slot element (n, 8s+u) lives at s*1024 + n*8 + u
__device__ __forceinline__ void store_h_slot(f16 (*hst)[8], f16* slotbase, int s,
                                             int tid, int n1, int u,
                                             float hv0, float hv1)
{
    hst[n1     ][u] = (f16)hv0;
    hst[n1 + 64][u] = (f16)hv1;
    __syncthreads();
    if (tid < 128) {
        union { v8f16 v; unsigned long long q[2]; } c;
        c.v = *(const v8f16*)&hst[tid][0];
        unsigned long long* gp = (unsigned long long*)(slotbase + ((size_t)s << 10) + (tid << 3));
        __hip_atomic_store(gp,     c.q[0], __ATOMIC_RELAXED, __HIP_MEMORY_SCOPE_AGENT);
        __hip_atomic_store(gp + 1, c.q[1], __ATOMIC_RELAXED, __HIP_MEMORY_SCOPE_AGENT);
    }
}

template<bool XF16>
__global__ void __launch_bounds__(512)
lstm_main(const float* __restrict__ x, const f16* __restrict__ xf,
          const f16* __restrict__ wsW, const float* __restrict__ wsB,
          f16* __restrict__ hseq, const float* __restrict__ c0,
          float* __restrict__ out, unsigned* __restrict__ bar)
{
    __shared__ f16   wlds[32][2056];   // 131584 B
    __shared__ float glds[128][36];    //  18432 B (2-way max conflicts)
    __shared__ f16   hst[128][8];      //   2048 B h-store staging

    const int tid   = threadIdx.x;
    const int wgid  = blockIdx.x;
    const int layer = wgid >> 7;
    const int s     = wgid & 127;
    const int lane  = tid & 63;
    const int wave  = tid >> 6;
    const int quad  = lane >> 4;
    const int l15   = lane & 15;
    const int rb    = wave & 3;        // rows [32rb, 32rb+32)
    const int ks    = wave >> 2;       // K-split (512-half slices per phase)

    for (int idx = tid; idx < 8192; idx += 512) {
        int cc = idx >> 8;
        int k8 = (idx & 255) << 3;
        int col = ((cc >> 3) << 10) + (s << 3) + (cc & 7);
        *(v8f16*)(&wlds[cc][k8]) =
            *(const v8f16*)(wsW + (((size_t)(layer*4096 + col)) << 11) + k8);
    }

    const int u  = tid & 7;
    const int jg = (s << 3) + u;
    const float bi = wsB[layer*4096 +        jg];
    const float bf = wsB[layer*4096 + 1024 + jg];
    const float bg = wsB[layer*4096 + 2048 + jg];
    const float bo = wsB[layer*4096 + 3072 + jg];
    const int n1 = tid >> 3;
    float cr0 = c0[((size_t)layer << 17) + ((size_t)n1 << 10) + jg];
    float cr1 = c0[((size_t)layer << 17) + ((size_t)(n1 + 64) << 10) + jg];

    __syncthreads();

    const int kq   = quad << 3;
    const int row0 = (rb << 5) + l15;
    const int kslc = ks << 9;                       // 512-half K-slice offset
    const int arow = (row0 << 10) + kslc + kq;      // row-major (xf) A offset
    const int jrow = (((kslc + kq) >> 3) << 10) + (row0 << 3);  // s-major A offset

    f16* h0b = hseq;
    f16* h1b = hseq + HS_BANK;
    unsigned* f0 = bar;             // dense: f0[s] = last finished l0 step+1
    unsigned* f1 = bar + 128;       // dense: f1[s]

    v8f16 A0[CHUNK], A1[CHUNK], C0[CHUNK], C1[CHUNK];

    if (layer == 0) {
        for (int t = 0; t < TSTEPS; ++t) {
            v4f32 acc[2][2] = {};

            // ---- independent phase: x[t] @ Wih (before the flag!) ----
            if (XF16) {
                const f16* xp = xf + ((size_t)t << 17) + arow;
                load_row(xp, 0,   A0, A1);
                load_row(xp, 256, C0, C1);
                KA16(A0, A1);                       // vmcnt(16): first batch
                mfma_chunk(A0, A1, wlds, l15, kq, kslc,       acc);
                KA16(C0, C1);                       // vmcnt(0)
                mfma_chunk(C0, C1, wlds, l15, kq, kslc + 256, acc);
            } else {
                const float* p0 = x + ((size_t)t << 17) + arow;
                const float* p1 = p0 + (16 << 10);
                #pragma unroll
                for (int k = 0; k < 512; k += 32) {
                    v4f32 w0 = *(const v4f32*)(p0 + k), w1 = *(const v4f32*)(p0 + k + 4);
                    v4f32 y0 = *(const v4f32*)(p1 + k), y1 = *(const v4f32*)(p1 + k + 4);
                    v8f16 a0 = cvt8(w0, w1);
                    v8f16 a1 = cvt8(y0, y1);
                    v8f16 b0 = *(const v8f16*)(&wlds[l15     ][kslc + k + kq]);
                    v8f16 b1 = *(const v8f16*)(&wlds[16 + l15][kslc + k + kq]);
                    acc[0][0] = __builtin_amdgcn_mfma_f32_16x16x32_f16(a0, b0, acc[0][0], 0, 0, 0);
                    acc[0][1] = __builtin_amdgcn_mfma_f32_16x16x32_f16(a0, b1, acc[0][1], 0, 0, 0);
                    acc[1][0] = __builtin_amdgcn_mfma_f32_16x16x32_f16(a1, b0, acc[1][0], 0, 0, 0);
                    acc[1][1] = __builtin_amdgcn_mfma_f32_16x16x32_f16(a1, b1, acc[1][1], 0, 0, 0);
                }
            }

            // ---- wait: all 128 l0 WGs finished step t-1 (single-wave poll) ----
            if (t > 0) {
                if (tid < 64) {
                    const unsigned long long* fp = (const unsigned long long*)f0 + tid;
                    unsigned need = (unsigned)t;
                    for (;;) {
                        unsigned long long v = ld_pair(fp);
                        if ((unsigned)v >= need && (unsigned)(v >> 32) >= need) break;
                        __builtin_amdgcn_s_sleep(3);
                    }
                }
                __syncthreads();
            }

            // ---- dependent phase: h[t] @ Whh, full 32-load batch ----
            {
                const f16* hp = h0b + (size_t)t * SLOT + jrow;
                load_sm(hp, 0,     A0, A1);
                load_sm(hp, 32768, C0, C1);
                KA16(A0, A1);                       // vmcnt(16)
                mfma_chunk(A0, A1, wlds, l15, kq, 1024 + kslc,       acc);
                KA16(C0, C1);                       // vmcnt(0)
                mfma_chunk(C0, C1, wlds, l15, kq, 1024 + kslc + 256, acc);
            }

            reduce_splits(acc, glds, rb, quad, l15, ks);

            float hv0, hv1;
            cell2(glds, n1, u, bi, bf, bg, bo, cr0, cr1, hv0, hv1);
            store_h_slot(hst, h0b + (size_t)(t + 1) * SLOT, s, tid, n1, u, hv0, hv1);

            __syncthreads();   // drains the agent stores (vmcnt) per wave
            if (tid == 0)
                __hip_atomic_store(f0 + s, (unsigned)(t + 1),
                                   __ATOMIC_RELAXED, __HIP_MEMORY_SCOPE_AGENT);
        }
    } else {
        v8f16 D0[CHUNK], D1[CHUNK];
        for (int t = 0; t < TSTEPS; ++t) {
            // wait: own recurrence h1[t] (f1 >= t) and input h0-out[t] (f0 >= t+1)
            if (tid < 64) {
                if (t > 0) {
                    const unsigned long long* fp = (const unsigned long long*)f1 + tid;
                    unsigned need = (unsigned)t;
                    for (;;) {
                        unsigned long long v = ld_pair(fp);
                        if ((unsigned)v >= need && (unsigned)(v >> 32) >= need) break;
                        __builtin_amdgcn_s_sleep(3);
                    }
                }
                {
                    const unsigned long long* fp = (const unsigned long long*)f0 + tid;
                    unsigned need = (unsigned)(t + 1);
                    for (;;) {
                        unsigned long long v = ld_pair(fp);
                        if ((unsigned)v >= need && (unsigned)(v >> 32) >= need) break;
                        __builtin_amdgcn_s_sleep(3);
                    }
                }
            }
            __syncthreads();

            v4f32 acc[2][2] = {};
            const f16* pp = h1b + (size_t)t * SLOT + jrow;         // own recurrence (critical)
            const f16* qp = h0b + (size_t)(t + 1) * SLOT + jrow;   // layer-0 out

            // 4-batch pipeline: P0,P1 batched; Q0,Q1 fly under P MFMAs.
            load_sm(pp, 0,     A0, A1);
            load_sm(pp, 32768, C0, C1);
            KA16(A0, A1);                                          // vmcnt(16)
            mfma_chunk(A0, A1, wlds, l15, kq, 1024 + kslc,       acc);
            load_sm(qp, 0,     D0, D1);                            // issue Q0
            KA16(C0, C1);                                          // vmcnt(16)
            mfma_chunk(C0, C1, wlds, l15, kq, 1024 + kslc + 256, acc);
            load_sm(qp, 32768, A0, A1);                            // issue Q1 (reuse A regs)
            KA16(D0, D1);                                          // vmcnt(16)
            mfma_chunk(D0, D1, wlds, l15, kq, kslc,       acc);
            KA16(A0, A1);                                          // vmcnt(0)
            mfma_chunk(A0, A1, wlds, l15, kq, kslc + 256, acc);

            reduce_splits(acc, glds, rb, quad, l15, ks);

            float hv0, hv1;
            cell2(glds, n1, u, bi, bf, bg, bo, cr0, cr1, hv0, hv1);
            if (t < TSTEPS - 1) {
                store_h_slot(hst, h1b + (size_t)(t + 1) * SLOT, s, tid, n1, u, hv0, hv1);
                __syncthreads();
                if (tid == 0)
                    __hip_atomic_store(f1 + s, (unsigned)(t + 1),
                                       __ATOMIC_RELAXED, __HIP_MEMORY_SCOPE_AGENT);
            } else {
                out[(n1 << 10) + jg] = hv0;
                out[((n1 + 64) << 10) + jg] = hv1;
            }
        }
    }
}

extern "C" void kernel_launch(void* const* d_in, const int* in_sizes, int n_in,
                              void* d_out, int out_size, void* d_ws, size_t ws_size,
                              hipStream_t stream) {
    const float* x   = (const float*)d_in[0];
    const float* h0  = (const float*)d_in[1];
    const float* c0  = (const float*)d_in[2];
    const float* Wih = (const float*)d_in[3];
    const float* Whh = (const float*)d_in[4];
    const float* bih = (const float*)d_in[5];
    const float* bhh = (const float*)d_in[6];
    float* out = (float*)d_out;

    char* ws = (char*)d_ws;
    const bool xf16 = (ws_size >= NEED2);

    f16*      wsW  = (f16*)ws;
    float*    wsB  = (float*)(ws + SZ_W);
    f16*      hseq = (f16*)(ws + SZ_W + SZ_B);
    unsigned* bar  = (unsigned*)(ws + SZ_W + SZ_B + SZ_HSEQ);
    f16*      xf   = (f16*)(ws + NEED1);
    int do_xf = xf16 ? 1 : 0;

    lstm_init<<<2048, 256, 0, stream>>>(x, h0, Wih, Whh, bih, bhh,
                                        wsW, wsB, hseq, bar, xf, do_xf);

    void* kargs[] = { (void*)&x, (void*)&xf, (void*)&wsW, (void*)&wsB,
                      (void*)&hseq, (void*)&c0, (void*)&out, (void*)&bar };
    if (xf16) {
        hipLaunchCooperativeKernel((void*)&lstm_main<true>, dim3(256), dim3(512), kargs, 0, stream);
    } else {
        hipLaunchCooperativeKernel((void*)&lstm_main<false>, dim3(256), dim3(512), kargs, 0, stream);
    }
}

// Round 4
// 3412.439 us; speedup vs baseline: 1.0920x; 1.0920x over previous
//
#include <hip/hip_runtime.h>

// LSTM T=256, N=128, D=H=1024, L=2.  Persistent cooperative kernel, 256 WGs x 512.
// WG (layer l, slice s) owns hidden units [8s,8s+8) => 32 gate cols, weights in LDS.
// Round-8: revert to round-6 structure (3294us: s-major slots, 16-B-strided flags,
// 128-thread poll, sleep(1)) and replace the load path with inline-asm
// global_load_dwordx4 + hand-counted s_waitcnt vmcnt(N):
//   - each of the 32 A-fragments of a phase is a distinct C variable written by
//     "=v" asm => RA must give distinct 4-VGPR tuples, no WAW window rotation,
//     all 32 loads in flight (round-4..7 evidence: compiler caps MLP at ~8).
//   - counted waits: issue 32, vmcnt(16) -> consume batch0, vmcnt(0) -> batch1.
//   - layer-1: 64 loads through 2 reg blocks (P->A,C; Q0 reuses A after consume,
//     Q1 reuses C), waits 16/16/16/0.  Counting is exact: no other VMEM op is
//     outstanding inside a phase (polls/stores are drained before issue).
//   - voffsets are per-lane loop-invariant (precomputed); per-step slot base is
//     wave-uniform via "s" constraint; +16K/+32K-half halves via 2nd SGPR base,
//     +128/+256-half companions via offset: imm.

typedef _Float16 f16;
typedef f16  v8f16 __attribute__((ext_vector_type(8)));
typedef float v4f32 __attribute__((ext_vector_type(4)));

#define TSTEPS 256
#define SLOT   131072u
static constexpr size_t HS_BANK = (size_t)258 * SLOT;   // elems per layer bank

#define SZ_W     ((size_t)2*4096*2048*2)   /* fp16 weights [l][col][k2048] */
#define SZ_B     ((size_t)2*4096*4)        /* fused bias fp32 */
#define SZ_HSEQ  ((size_t)2*258*SLOT*2)    /* h slots, 2 banks, fp16 */
#define SZ_BAR   ((size_t)4096)            /* 2 layers x 128 flags x 16 B */
#define SZ_XF    ((size_t)256*128*1024*2)  /* x in fp16 */
#define NEED1    (SZ_W + SZ_B + SZ_HSEQ + SZ_BAR)
#define NEED2    (NEED1 + SZ_XF)

__global__ void lstm_init(const float* __restrict__ x,
                          const float* __restrict__ h0,
                          const float* __restrict__ Wih, const float* __restrict__ Whh,
                          const float* __restrict__ bih, const float* __restrict__ bhh,
                          f16* __restrict__ wsW, float* __restrict__ wsB,
                          f16* __restrict__ hseq, unsigned* __restrict__ bar,
                          f16* __restrict__ xf, int do_xf)
{
    size_t tid  = (size_t)blockIdx.x * blockDim.x + threadIdx.x;
    size_t nthr = (size_t)gridDim.x * blockDim.x;
    // weights: [l][col][k], k<1024 -> W_ih, k>=1024 -> W_hh
    for (size_t i = tid; i < 16777216u; i += nthr) {
        unsigned l = (unsigned)(i >> 23), rem = (unsigned)(i & 8388607u);
        unsigned col = rem >> 11, k = rem & 2047u;
        float v = (k < 1024u) ? Wih[(size_t)l*4194304u + (size_t)col*1024u + k]
                              : Whh[(size_t)l*4194304u + (size_t)col*1024u + (k-1024u)];
        wsW[i] = (f16)v;
    }
    for (size_t i = tid; i < 8192u; i += nthr) wsB[i] = bih[i] + bhh[i];
    // initial h slots in s-major layout: (n,k) -> (k>>3)*1024 + n*8 + (k&7)
    for (size_t i = tid; i < 131072u; i += nthr) {
        unsigned n = (unsigned)(i >> 10), k = (unsigned)(i & 1023u);
        unsigned dst = ((k >> 3) << 10) + (n << 3) + (k & 7u);
        hseq[dst]           = (f16)h0[i];             // layer0 slot 0
        hseq[HS_BANK + dst] = (f16)h0[131072u + i];   // layer1 slot 0
    }
    for (size_t i = tid; i < 1024u; i += nthr) bar[i] = 0u;   // all flags
    if (do_xf) {
        for (size_t i = tid; i < 33554432u; i += nthr) xf[i] = (f16)x[i];
    }
}

__device__ __forceinline__ float sigmoid_fast(float v) { return 1.0f / (1.0f + __expf(-v)); }
__device__ __forceinline__ float tanh_fast(float v)    { return 1.0f - 2.0f / (__expf(2.0f*v) + 1.0f); }

__device__ __forceinline__ v8f16 cvt8(v4f32 lo, v4f32 hi) {
    v8f16 r;
    r[0]=(f16)lo[0]; r[1]=(f16)lo[1]; r[2]=(f16)lo[2]; r[3]=(f16)lo[3];
    r[4]=(f16)hi[0]; r[5]=(f16)hi[1]; r[6]=(f16)hi[2]; r[7]=(f16)hi[3];
    return r;
}

__device__ __forceinline__ unsigned ld_cnt(const unsigned* p) {
    return __hip_atomic_load(p, __ATOMIC_RELAXED, __HIP_MEMORY_SCOPE_AGENT);
}

#define CHUNK 8

// ---- inline-asm load path: compiler cannot window these dest registers ----
#define GLOAD(d, base, voff) \
    asm volatile("global_load_dwordx4 %0, %1, %2" : "=v"(d) : "v"(voff), "s"(base))
#define GLOADO256(d, base, voff) \
    asm volatile("global_load_dwordx4 %0, %1, %2 offset:256" : "=v"(d) : "v"(voff), "s"(base))
#define GLOADO512(d, base, voff) \
    asm volatile("global_load_dwordx4 %0, %1, %2 offset:512" : "=v"(d) : "v"(voff), "s"(base))
#define WAITV16 { asm volatile("s_waitcnt vmcnt(16)"); __builtin_amdgcn_sched_barrier(0); }
#define WAITV0  { asm volatile("s_waitcnt vmcnt(0)");  __builtin_amdgcn_sched_barrier(0); }

// issue 16 loads (one batch) from an s-major h slot: base + voff[i], companion +256B
__device__ __forceinline__ void issue_sm(const f16* base, const unsigned vo[8],
                                         v8f16 a0[CHUNK], v8f16 a1[CHUNK])
{
    #pragma unroll
    for (int i = 0; i < CHUNK; ++i) { GLOAD(a0[i], base, vo[i]); GLOADO256(a1[i], base, vo[i]); }
}

// consume one 8-iteration chunk (B from LDS weights)
__device__ __forceinline__ void mfma_chunk(const v8f16 a0[CHUNK], const v8f16 a1[CHUNK],
                                           const f16 (*wl)[2056], int l15, int kq, int kbase,
                                           v4f32 acc[2][2])
{
    #pragma unroll
    for (int i = 0; i < CHUNK; ++i) {
        int k = kbase + 32*i;
        v8f16 b0 = *(const v8f16*)(&wl[l15     ][k + kq]);
        v8f16 b1 = *(const v8f16*)(&wl[16 + l15][k + kq]);
        acc[0][0] = __builtin_amdgcn_mfma_f32_16x16x32_f16(a0[i], b0, acc[0][0], 0, 0, 0);
        acc[0][1] = __builtin_amdgcn_mfma_f32_16x16x32_f16(a0[i], b1, acc[0][1], 0, 0, 0);
        acc[1][0] = __builtin_amdgcn_mfma_f32_16x16x32_f16(a1[i], b0, acc[1][0], 0, 0, 0);
        acc[1][1] = __builtin_amdgcn_mfma_f32_16x16x32_f16(a1[i], b1, acc[1][1], 0, 0, 0);
    }
}

__device__ __forceinline__ void reduce_splits(v4f32 acc[2][2], float (*gl)[36],
                                              int rb, int quad, int l15, int ks)
{
    if (ks == 0) {
        #pragma unroll
        for (int mt = 0; mt < 2; ++mt) {
            int rrow = (rb << 5) + (mt << 4) + (quad << 2);
            #pragma unroll
            for (int r = 0; r < 4; ++r) {
                gl[rrow + r][l15     ] = acc[mt][0][r];
                gl[rrow + r][16 + l15] = acc[mt][1][r];
            }
        }
    }
    __syncthreads();
    if (ks == 1) {
        #pragma unroll
        for (int mt = 0; mt < 2; ++mt) {
            int rrow = (rb << 5) + (mt << 4) + (quad << 2);
            #pragma unroll
            for (int r = 0; r < 4; ++r) {
                gl[rrow + r][l15     ] += acc[mt][0][r];
                gl[rrow + r][16 + l15] += acc[mt][1][r];
            }
        }
    }
    __syncthreads();
}

__device__ __forceinline__ void cell2(const float (*gl)[36], int n1, int u,
                                      float bi, float bf, float bg, float bo,
                                      float& cr0, float& cr1, float& h0o, float& h1o)
{
    {
        float gi = gl[n1][u]      + bi;
        float gf = gl[n1][8 + u]  + bf;
        float gg = gl[n1][16 + u] + bg;
        float go = gl[n1][24 + u] + bo;
        float cn = sigmoid_fast(gf) * cr0 + sigmoid_fast(gi) * tanh_fast(gg);
        cr0 = cn;
        h0o = sigmoid_fast(go) * tanh_fast(cn);
    }
    {
        int n = n1 + 64;
        float gi = gl[n][u]      + bi;
        float gf = gl[n][8 + u]  + bf;
        float gg = gl[n][16 + u] + bg;
        float go = gl[n][24 + u] + bo;
        float cn = sigmoid_fast(gf) * cr1 + sigmoid_fast(gi) * tanh_fast(gg);
        cr1 = cn;
        h1o = sigmoid_fast(go) * tanh_fast(cn);
    }
}

// stage hv in LDS, then 128 threads store the WG's CONTIGUOUS 2 KB region:
// slot element (n, 8s+u) lives at s*1024 + n*8 + u
__device__ __forceinline__ void store_h_slot(f16 (*hst)[8], f16* slotbase, int s,
                                             int tid, int n1, int u,
                                             float hv0, float hv1)
{
    hst[n1     ][u] = (f16)hv0;
    hst[n1 + 64][u] = (f16)hv1;
    __syncthreads();
    if (tid < 128) {
        union { v8f16 v; unsigned long long q[2]; } c;
        c.v = *(const v8f16*)&hst[tid][0];
        unsigned long long* gp = (unsigned long long*)(slotbase + ((size_t)s << 10) + (tid << 3));
        __hip_atomic_store(gp,     c.q[0], __ATOMIC_RELAXED, __HIP_MEMORY_SCOPE_AGENT);
        __hip_atomic_store(gp + 1, c.q[1], __ATOMIC_RELAXED, __HIP_MEMORY_SCOPE_AGENT);
    }
}

template<bool XF16>
__global__ void __launch_bounds__(512)
lstm_main(const float* __restrict__ x, const f16* __restrict__ xf,
          const f16* __restrict__ wsW, const float* __restrict__ wsB,
          f16* __restrict__ hseq, const float* __restrict__ c0,
          float* __restrict__ out, unsigned* __restrict__ bar)
{
    __shared__ f16   wlds[32][2056];   // 131584 B
    __shared__ float glds[128][36];    //  18432 B (2-way max conflicts)
    __shared__ f16   hst[128][8];      //   2048 B h-store staging

    const int tid   = threadIdx.x;
    const int wgid  = blockIdx.x;
    const int layer = wgid >> 7;
    const int s     = wgid & 127;
    const int lane  = tid & 63;
    const int wave  = tid >> 6;
    const int quad  = lane >> 4;
    const int l15   = lane & 15;
    const int rb    = wave & 3;        // rows [32rb, 32rb+32)
    const int ks    = wave >> 2;       // K-split (512-half slices per phase)

    for (int idx = tid; idx < 8192; idx += 512) {
        int cc = idx >> 8;
        int k8 = (idx & 255) << 3;
        int col = ((cc >> 3) << 10) + (s << 3) + (cc & 7);
        *(v8f16*)(&wlds[cc][k8]) =
            *(const v8f16*)(wsW + (((size_t)(layer*4096 + col)) << 11) + k8);
    }

    const int u  = tid & 7;
    const int jg = (s << 3) + u;
    const float bi = wsB[layer*4096 +        jg];
    const float bf = wsB[layer*4096 + 1024 + jg];
    const float bg = wsB[layer*4096 + 2048 + jg];
    const float bo = wsB[layer*4096 + 3072 + jg];
    const int n1 = tid >> 3;
    float cr0 = c0[((size_t)layer << 17) + ((size_t)n1 << 10) + jg];
    float cr1 = c0[((size_t)layer << 17) + ((size_t)(n1 + 64) << 10) + jg];

    __syncthreads();

    const int kq   = quad << 3;
    const int row0 = (rb << 5) + l15;
    const int kslc = ks << 9;                       // 512-half K-slice offset
    const int arow = (row0 << 10) + kslc + kq;      // row-major (xf) A offset
    const int jrow = (((kslc + kq) >> 3) << 10) + (row0 << 3);  // s-major A offset

    // loop-invariant per-lane byte voffsets
    unsigned vox[8], voh[8];
    #pragma unroll
    for (int i = 0; i < 8; ++i) {
        vox[i] = (unsigned)((arow + 32*i) * 2);
        voh[i] = (unsigned)((jrow + 4096*i) * 2);
    }

    f16* h0b = hseq;
    f16* h1b = hseq + HS_BANK;
    unsigned* f0 = bar;             // f0[s*4] = last finished l0 step+1 (16-B stride)
    unsigned* f1 = bar + 512;       // f1[s*4]

    v8f16 A0[CHUNK], A1[CHUNK], C0[CHUNK], C1[CHUNK];

    if (layer == 0) {
        for (int t = 0; t < TSTEPS; ++t) {
            v4f32 acc[2][2] = {};

            // ---- independent phase: x[t] @ Wih (before the flag!) ----
            if (XF16) {
                const f16* sx  = xf + ((size_t)t << 17);
                const f16* sx2 = sx + 16384;                  // rows +16
                #pragma unroll
                for (int i = 0; i < 8; ++i) { GLOAD(A0[i], sx, vox[i]); GLOAD(A1[i], sx2, vox[i]); }
                #pragma unroll
                for (int i = 0; i < 8; ++i) { GLOADO512(C0[i], sx, vox[i]); GLOADO512(C1[i], sx2, vox[i]); }
                WAITV16;
                mfma_chunk(A0, A1, wlds, l15, kq, kslc,       acc);
                WAITV0;
                mfma_chunk(C0, C1, wlds, l15, kq, kslc + 256, acc);
            } else {
                const float* p0 = x + ((size_t)t << 17) + arow;
                const float* p1 = p0 + (16 << 10);
                #pragma unroll
                for (int k = 0; k < 512; k += 32) {
                    v4f32 w0 = *(const v4f32*)(p0 + k), w1 = *(const v4f32*)(p0 + k + 4);
                    v4f32 y0 = *(const v4f32*)(p1 + k), y1 = *(const v4f32*)(p1 + k + 4);
                    v8f16 a0 = cvt8(w0, w1);
                    v8f16 a1 = cvt8(y0, y1);
                    v8f16 b0 = *(const v8f16*)(&wlds[l15     ][kslc + k + kq]);
                    v8f16 b1 = *(const v8f16*)(&wlds[16 + l15][kslc + k + kq]);
                    acc[0][0] = __builtin_amdgcn_mfma_f32_16x16x32_f16(a0, b0, acc[0][0], 0, 0, 0);
                    acc[0][1] = __builtin_amdgcn_mfma_f32_16x16x32_f16(a0, b1, acc[0][1], 0, 0, 0);
                    acc[1][0] = __builtin_amdgcn_mfma_f32_16x16x32_f16(a1, b0, acc[1][0], 0, 0, 0);
                    acc[1][1] = __builtin_amdgcn_mfma_f32_16x16x32_f16(a1, b1, acc[1][1], 0, 0, 0);
                }
            }

            // ---- wait: all 128 l0 WGs finished step t-1 (parallel poll) ----
            if (t > 0) {
                if (tid < 128) {
                    const unsigned* fp = f0 + (tid << 2);
                    unsigned need = (unsigned)t;
                    while (ld_cnt(fp) < need) __builtin_amdgcn_s_sleep(1);
                }
                __syncthreads();
            }

            // ---- dependent phase: h[t] @ Whh, 32 loads in flight ----
            {
                const f16* sh  = h0b + (size_t)t * SLOT;
                const f16* sh2 = sh + 32768;
                issue_sm(sh,  voh, A0, A1);
                issue_sm(sh2, voh, C0, C1);
                WAITV16;
                mfma_chunk(A0, A1, wlds, l15, kq, 1024 + kslc,       acc);
                WAITV0;
                mfma_chunk(C0, C1, wlds, l15, kq, 1024 + kslc + 256, acc);
            }

            reduce_splits(acc, glds, rb, quad, l15, ks);

            float hv0, hv1;
            cell2(glds, n1, u, bi, bf, bg, bo, cr0, cr1, hv0, hv1);
            store_h_slot(hst, h0b + (size_t)(t + 1) * SLOT, s, tid, n1, u, hv0, hv1);

            __syncthreads();   // drains the agent stores (vmcnt) per wave
            if (tid == 0)
                __hip_atomic_store(f0 + (s << 2), (unsigned)(t + 1),
                                   __ATOMIC_RELAXED, __HIP_MEMORY_SCOPE_AGENT);
        }
    } else {
        for (int t = 0; t < TSTEPS; ++t) {
            // wait: own recurrence h1[t] (f1 >= t) and input h0-out[t] (f0 >= t+1)
            if (tid < 128) {
                if (t > 0) {
                    const unsigned* fp = f1 + (tid << 2);
                    unsigned need = (unsigned)t;
                    while (ld_cnt(fp) < need) __builtin_amdgcn_s_sleep(1);
                }
            } else if (tid < 256) {
                const unsigned* fp = f0 + ((tid - 128) << 2);
                unsigned need = (unsigned)(t + 1);
                while (ld_cnt(fp) < need) __builtin_amdgcn_s_sleep(1);
            }
            __syncthreads();

            v4f32 acc[2][2] = {};
            const f16* sp  = h1b + (size_t)t * SLOT;           // own recurrence (critical)
            const f16* sp2 = sp + 32768;
            const f16* sq  = h0b + (size_t)(t + 1) * SLOT;     // layer-0 out
            const f16* sq2 = sq + 32768;

            // 64 loads through 2 reg blocks; counted waits 16/16/16/0
            issue_sm(sp,  voh, A0, A1);                        // P0 (16)
            issue_sm(sp2, voh, C0, C1);                        // P1 (16) -> 32 out
            WAITV16;                                           // P0 ready
            mfma_chunk(A0, A1, wlds, l15, kq, 1024 + kslc,       acc);
            issue_sm(sq,  voh, A0, A1);                        // Q0 reuses A -> 32 out
            WAITV16;                                           // P1 ready
            mfma_chunk(C0, C1, wlds, l15, kq, 1024 + kslc + 256, acc);
            issue_sm(sq2, voh, C0, C1);                        // Q1 reuses C -> 32 out
            WAITV16;                                           // Q0 ready
            mfma_chunk(A0, A1, wlds, l15, kq, kslc,       acc);
            WAITV0;                                            // Q1 ready
            mfma_chunk(C0, C1, wlds, l15, kq, kslc + 256, acc);

            reduce_splits(acc, glds, rb, quad, l15, ks);

            float hv0, hv1;
            cell2(glds, n1, u, bi, bf, bg, bo, cr0, cr1, hv0, hv1);
            if (t < TSTEPS - 1) {
                store_h_slot(hst, h1b + (size_t)(t + 1) * SLOT, s, tid, n1, u, hv0, hv1);
                __syncthreads();
                if (tid == 0)
                    __hip_atomic_store(f1 + (s << 2), (unsigned)(t + 1),
                                       __ATOMIC_RELAXED, __HIP_MEMORY_SCOPE_AGENT);
            } else {
                out[(n1 << 10) + jg] = hv0;
                out[((n1 + 64) << 10) + jg] = hv1;
            }
        }
    }
}

extern "C" void kernel_launch(void* const* d_in, const int* in_sizes, int n_in,
                              void* d_out, int out_size, void* d_ws, size_t ws_size,
                              hipStream_t stream) {
    const float* x   = (const float*)d_in[0];
    const float* h0  = (const float*)d_in[1];
    const float* c0  = (const float*)d_in[2];
    const float* Wih = (const float*)d_in[3];
    const float* Whh = (const float*)d_in[4];
    const float* bih = (const float*)d_in[5];
    const float* bhh = (const float*)d_in[6];
    float* out = (float*)d_out;

    char* ws = (char*)d_ws;
    const bool xf16 = (ws_size >= NEED2);

    f16*      wsW  = (f16*)ws;
    float*    wsB  = (float*)(ws + SZ_W);
    f16*      hseq = (f16*)(ws + SZ_W + SZ_B);
    unsigned* bar  = (unsigned*)(ws + SZ_W + SZ_B + SZ_HSEQ);
    f16*      xf   = (f16*)(ws + NEED1);
    int do_xf = xf16 ? 1 : 0;

    lstm_init<<<2048, 256, 0, stream>>>(x, h0, Wih, Whh, bih, bhh,
                                        wsW, wsB, hseq, bar, xf, do_xf);

    void* kargs[] = { (void*)&x, (void*)&xf, (void*)&wsW, (void*)&wsB,
                      (void*)&hseq, (void*)&c0, (void*)&out, (void*)&bar };
    if (xf16) {
        hipLaunchCooperativeKernel((void*)&lstm_main<true>, dim3(256), dim3(512), kargs, 0, stream);
    } else {
        hipLaunchCooperativeKernel((void*)&lstm_main<false>, dim3(256), dim3(512), kargs, 0, stream);
    }
}

// Round 5
// 3138.727 us; speedup vs baseline: 1.1872x; 1.0872x over previous
//
#include <hip/hip_runtime.h>

// LSTM T=256, N=128, D=H=1024, L=2.  Persistent cooperative kernel, 256 WGs x 512.
// WG (layer l, slice s) owns hidden units [8s,8s+8) => 32 gate cols, weights in LDS.
// Round-9 (base = round-6/3294us structure; r7/r8 load-side changes falsified the
// MLP theory, reverted).  New theory: l0's self-recurrence is the ONLY binding
// loop (l0 never waits on l1); its ~13us cycle >> ~3us serial chain because l1's
// 64MB/step broadcast bursts + poll storms queue l0's store->flag->poll->load
// chain in the shared per-XCD L2s, and the step time is the max over 128 WGs.
// Changes:
//  (1) XCD partition: blockIdx remapped so l0 -> XCDs 0-3, l1 -> XCDs 4-7
//      (bid%8 heuristic; wrong mapping degenerates to the status quo).
//  (2) Dual flag lines: l0 writes f0a (polled by l0 peers) and f0b (polled by
//      l1) so l1's poll traffic never touches l0's hot lines.
//  (3) l1 slack restructure: poll f0b -> issue Q loads -> poll own f1 while Q
//      is in flight -> P loads -> MFMAs; l1 polls at s_sleep(2).
//  (4) Load path = round-2 form (compiler loads + sched_barrier(0)).

typedef _Float16 f16;
typedef f16  v8f16 __attribute__((ext_vector_type(8)));
typedef float v4f32 __attribute__((ext_vector_type(4)));

#define TSTEPS 256
#define SLOT   131072u
static constexpr size_t HS_BANK = (size_t)258 * SLOT;   // elems per layer bank

#define SZ_W     ((size_t)2*4096*2048*2)   /* fp16 weights [l][col][k2048] */
#define SZ_B     ((size_t)2*4096*4)        /* fused bias fp32 */
#define SZ_HSEQ  ((size_t)2*258*SLOT*2)    /* h slots, 2 banks, fp16 */
#define SZ_BAR   ((size_t)8192)            /* f0a / f0b / f1, 128 x 16B each */
#define SZ_XF    ((size_t)256*128*1024*2)  /* x in fp16 */
#define NEED1    (SZ_W + SZ_B + SZ_HSEQ + SZ_BAR)
#define NEED2    (NEED1 + SZ_XF)

__global__ void lstm_init(const float* __restrict__ x,
                          const float* __restrict__ h0,
                          const float* __restrict__ Wih, const float* __restrict__ Whh,
                          const float* __restrict__ bih, const float* __restrict__ bhh,
                          f16* __restrict__ wsW, float* __restrict__ wsB,
                          f16* __restrict__ hseq, unsigned* __restrict__ bar,
                          f16* __restrict__ xf, int do_xf)
{
    size_t tid  = (size_t)blockIdx.x * blockDim.x + threadIdx.x;
    size_t nthr = (size_t)gridDim.x * blockDim.x;
    // weights: [l][col][k], k<1024 -> W_ih, k>=1024 -> W_hh
    for (size_t i = tid; i < 16777216u; i += nthr) {
        unsigned l = (unsigned)(i >> 23), rem = (unsigned)(i & 8388607u);
        unsigned col = rem >> 11, k = rem & 2047u;
        float v = (k < 1024u) ? Wih[(size_t)l*4194304u + (size_t)col*1024u + k]
                              : Whh[(size_t)l*4194304u + (size_t)col*1024u + (k-1024u)];
        wsW[i] = (f16)v;
    }
    for (size_t i = tid; i < 8192u; i += nthr) wsB[i] = bih[i] + bhh[i];
    // initial h slots in s-major layout: (n,k) -> (k>>3)*1024 + n*8 + (k&7)
    for (size_t i = tid; i < 131072u; i += nthr) {
        unsigned n = (unsigned)(i >> 10), k = (unsigned)(i & 1023u);
        unsigned dst = ((k >> 3) << 10) + (n << 3) + (k & 7u);
        hseq[dst]           = (f16)h0[i];             // layer0 slot 0
        hseq[HS_BANK + dst] = (f16)h0[131072u + i];   // layer1 slot 0
    }
    for (size_t i = tid; i < 2048u; i += nthr) bar[i] = 0u;   // all flags
    if (do_xf) {
        for (size_t i = tid; i < 33554432u; i += nthr) xf[i] = (f16)x[i];
    }
}

__device__ __forceinline__ float sigmoid_fast(float v) { return 1.0f / (1.0f + __expf(-v)); }
__device__ __forceinline__ float tanh_fast(float v)    { return 1.0f - 2.0f / (__expf(2.0f*v) + 1.0f); }

__device__ __forceinline__ v8f16 cvt8(v4f32 lo, v4f32 hi) {
    v8f16 r;
    r[0]=(f16)lo[0]; r[1]=(f16)lo[1]; r[2]=(f16)lo[2]; r[3]=(f16)lo[3];
    r[4]=(f16)hi[0]; r[5]=(f16)hi[1]; r[6]=(f16)hi[2]; r[7]=(f16)hi[3];
    return r;
}

__device__ __forceinline__ unsigned ld_cnt(const unsigned* p) {
    return __hip_atomic_load(p, __ATOMIC_RELAXED, __HIP_MEMORY_SCOPE_AGENT);
}

#define CHUNK 8

// row-major source (xf): rows stride 1024 halves, a1 = rows +16
__device__ __forceinline__ void load_row(const f16* p, int off,
                                         v8f16 a0[CHUNK], v8f16 a1[CHUNK])
{
    #pragma unroll
    for (int i = 0; i < CHUNK; ++i) {
        a0[i] = *(const v8f16*)(p + off + 32*i);
        a1[i] = *(const v8f16*)(p + off + 16384 + 32*i);
    }
}

// s-major h slot: element (n,k) at (k>>3)*1024 + n*8 + (k&7)
__device__ __forceinline__ void load_sm(const f16* p, int off,
                                        v8f16 a0[CHUNK], v8f16 a1[CHUNK])
{
    #pragma unroll
    for (int i = 0; i < CHUNK; ++i) {
        a0[i] = *(const v8f16*)(p + off + 4096*i);
        a1[i] = *(const v8f16*)(p + off + 128 + 4096*i);   // rows +16 -> +128 halves
    }
}

// consume one 8-iteration chunk (B from LDS weights)
__device__ __forceinline__ void mfma_chunk(const v8f16 a0[CHUNK], const v8f16 a1[CHUNK],
                                           const f16 (*wl)[2056], int l15, int kq, int kbase,
                                           v4f32 acc[2][2])
{
    #pragma unroll
    for (int i = 0; i < CHUNK; ++i) {
        int k = kbase + 32*i;
        v8f16 b0 = *(const v8f16*)(&wl[l15     ][k + kq]);
        v8f16 b1 = *(const v8f16*)(&wl[16 + l15][k + kq]);
        acc[0][0] = __builtin_amdgcn_mfma_f32_16x16x32_f16(a0[i], b0, acc[0][0], 0, 0, 0);
        acc[0][1] = __builtin_amdgcn_mfma_f32_16x16x32_f16(a0[i], b1, acc[0][1], 0, 0, 0);
        acc[1][0] = __builtin_amdgcn_mfma_f32_16x16x32_f16(a1[i], b0, acc[1][0], 0, 0, 0);
        acc[1][1] = __builtin_amdgcn_mfma_f32_16x16x32_f16(a1[i], b1, acc[1][1], 0, 0, 0);
    }
}

__device__ __forceinline__ void reduce_splits(v4f32 acc[2][2], float (*gl)[36],
                                              int rb, int quad, int l15, int ks)
{
    if (ks == 0) {
        #pragma unroll
        for (int mt = 0; mt < 2; ++mt) {
            int rrow = (rb << 5) + (mt << 4) + (quad << 2);
            #pragma unroll
            for (int r = 0; r < 4; ++r) {
                gl[rrow + r][l15     ] = acc[mt][0][r];
                gl[rrow + r][16 + l15] = acc[mt][1][r];
            }
        }
    }
    __syncthreads();
    if (ks == 1) {
        #pragma unroll
        for (int mt = 0; mt < 2; ++mt) {
            int rrow = (rb << 5) + (mt << 4) + (quad << 2);
            #pragma unroll
            for (int r = 0; r < 4; ++r) {
                gl[rrow + r][l15     ] += acc[mt][0][r];
                gl[rrow + r][16 + l15] += acc[mt][1][r];
            }
        }
    }
    __syncthreads();
}

__device__ __forceinline__ void cell2(const float (*gl)[36], int n1, int u,
                                      float bi, float bf, float bg, float bo,
                                      float& cr0, float& cr1, float& h0o, float& h1o)
{
    {
        float gi = gl[n1][u]      + bi;
        float gf = gl[n1][8 + u]  + bf;
        float gg = gl[n1][16 + u] + bg;
        float go = gl[n1][24 + u] + bo;
        float cn = sigmoid_fast(gf) * cr0 + sigmoid_fast(gi) * tanh_fast(gg);
        cr0 = cn;
        h0o = sigmoid_fast(go) * tanh_fast(cn);
    }
    {
        int n = n1 + 64;
        float gi = gl[n][u]      + bi;
        float gf = gl[n][8 + u]  + bf;
        float gg = gl[n][16 + u] + bg;
        float go = gl[n][24 + u] + bo;
        float cn = sigmoid_fast(gf) * cr1 + sigmoid_fast(gi) * tanh_fast(gg);
        cr1 = cn;
        h1o = sigmoid_fast(go) * tanh_fast(cn);
    }
}

// stage hv in LDS, then 128 threads store the WG's CONTIGUOUS 2 KB region:
// slot element (n, 8s+u) lives at s*1024 + n*8 + u
__device__ __forceinline__ void store_h_slot(f16 (*hst)[8], f16* slotbase, int s,
                                             int tid, int n1, int u,
                                             float hv0, float hv1)
{
    hst[n1     ][u] = (f16)hv0;
    hst[n1 + 64][u] = (f16)hv1;
    __syncthreads();
    if (tid < 128) {
        union { v8f16 v; unsigned long long q[2]; } c;
        c.v = *(const v8f16*)&hst[tid][0];
        unsigned long long* gp = (unsigned long long*)(slotbase + ((size_t)s << 10) + (tid << 3));
        __hip_atomic_store(gp,     c.q[0], __ATOMIC_RELAXED, __HIP_MEMORY_SCOPE_AGENT);
        __hip_atomic_store(gp + 1, c.q[1], __ATOMIC_RELAXED, __HIP_MEMORY_SCOPE_AGENT);
    }
}

template<bool XF16>
__global__ void __launch_bounds__(512)
lstm_main(const float* __restrict__ x, const f16* __restrict__ xf,
          const f16* __restrict__ wsW, const float* __restrict__ wsB,
          f16* __restrict__ hseq, const float* __restrict__ c0,
          float* __restrict__ out, unsigned* __restrict__ bar)
{
    __shared__ f16   wlds[32][2056];   // 131584 B
    __shared__ float glds[128][36];    //  18432 B (2-way max conflicts)
    __shared__ f16   hst[128][8];      //   2048 B h-store staging

    const int tid   = threadIdx.x;
    // XCD partition (dispatch heuristic: XCD = blockIdx % 8):
    // l0 -> XCDs 0-3, l1 -> XCDs 4-7; 32 WGs (= 32 CUs) of one layer per XCD.
    const int bid   = blockIdx.x;
    const int xcd   = bid & 7;
    const int layer = (xcd >> 2);              // 0 for XCD 0-3, 1 for XCD 4-7
    const int s     = (bid >> 3) * 4 + (xcd & 3);   // 0..127 within layer
    const int lane  = tid & 63;
    const int wave  = tid >> 6;
    const int quad  = lane >> 4;
    const int l15   = lane & 15;
    const int rb    = wave & 3;        // rows [32rb, 32rb+32)
    const int ks    = wave >> 2;       // K-split (512-half slices per phase)

    for (int idx = tid; idx < 8192; idx += 512) {
        int cc = idx >> 8;
        int k8 = (idx & 255) << 3;
        int col = ((cc >> 3) << 10) + (s << 3) + (cc & 7);
        *(v8f16*)(&wlds[cc][k8]) =
            *(const v8f16*)(wsW + (((size_t)(layer*4096 + col)) << 11) + k8);
    }

    const int u  = tid & 7;
    const int jg = (s << 3) + u;
    const float bi = wsB[layer*4096 +        jg];
    const float bf = wsB[layer*4096 + 1024 + jg];
    const float bg = wsB[layer*4096 + 2048 + jg];
    const float bo = wsB[layer*4096 + 3072 + jg];
    const int n1 = tid >> 3;
    float cr0 = c0[((size_t)layer << 17) + ((size_t)n1 << 10) + jg];
    float cr1 = c0[((size_t)layer << 17) + ((size_t)(n1 + 64) << 10) + jg];

    __syncthreads();

    const int kq   = quad << 3;
    const int row0 = (rb << 5) + l15;
    const int kslc = ks << 9;                       // 512-half K-slice offset
    const int arow = (row0 << 10) + kslc + kq;      // row-major (xf) A offset
    const int jrow = (((kslc + kq) >> 3) << 10) + (row0 << 3);  // s-major A offset

    f16* h0b = hseq;
    f16* h1b = hseq + HS_BANK;
    unsigned* f0a = bar;             // l0 peers poll this copy   (16-B stride)
    unsigned* f0b = bar + 512;       // l1 polls this copy
    unsigned* f1  = bar + 1024;      // l1 own-recurrence flags

    v8f16 A0[CHUNK], A1[CHUNK], C0[CHUNK], C1[CHUNK];

    if (layer == 0) {
        for (int t = 0; t < TSTEPS; ++t) {
            v4f32 acc[2][2] = {};

            // ---- independent phase: x[t] @ Wih (before the flag!) ----
            if (XF16) {
                const f16* xp = xf + ((size_t)t << 17) + arow;
                load_row(xp, 0,   A0, A1);
                load_row(xp, 256, C0, C1);
                __builtin_amdgcn_sched_barrier(0);
                mfma_chunk(A0, A1, wlds, l15, kq, kslc,       acc);
                mfma_chunk(C0, C1, wlds, l15, kq, kslc + 256, acc);
            } else {
                const float* p0 = x + ((size_t)t << 17) + arow;
                const float* p1 = p0 + (16 << 10);
                #pragma unroll
                for (int k = 0; k < 512; k += 32) {
                    v4f32 w0 = *(const v4f32*)(p0 + k), w1 = *(const v4f32*)(p0 + k + 4);
                    v4f32 y0 = *(const v4f32*)(p1 + k), y1 = *(const v4f32*)(p1 + k + 4);
                    v8f16 a0 = cvt8(w0, w1);
                    v8f16 a1 = cvt8(y0, y1);
                    v8f16 b0 = *(const v8f16*)(&wlds[l15     ][kslc + k + kq]);
                    v8f16 b1 = *(const v8f16*)(&wlds[16 + l15][kslc + k + kq]);
                    acc[0][0] = __builtin_amdgcn_mfma_f32_16x16x32_f16(a0, b0, acc[0][0], 0, 0, 0);
                    acc[0][1] = __builtin_amdgcn_mfma_f32_16x16x32_f16(a0, b1, acc[0][1], 0, 0, 0);
                    acc[1][0] = __builtin_amdgcn_mfma_f32_16x16x32_f16(a1, b0, acc[1][0], 0, 0, 0);
                    acc[1][1] = __builtin_amdgcn_mfma_f32_16x16x32_f16(a1, b1, acc[1][1], 0, 0, 0);
                }
            }

            // ---- wait: all 128 l0 WGs finished step t-1 (parallel poll) ----
            if (t > 0) {
                if (tid < 128) {
                    const unsigned* fp = f0a + (tid << 2);
                    unsigned need = (unsigned)t;
                    while (ld_cnt(fp) < need) __builtin_amdgcn_s_sleep(1);
                }
                __syncthreads();
            }

            // ---- dependent phase: h[t] @ Whh ----
            {
                const f16* hp = h0b + (size_t)t * SLOT + jrow;
                load_sm(hp, 0,     A0, A1);
                load_sm(hp, 32768, C0, C1);
                __builtin_amdgcn_sched_barrier(0);
                mfma_chunk(A0, A1, wlds, l15, kq, 1024 + kslc,       acc);
                mfma_chunk(C0, C1, wlds, l15, kq, 1024 + kslc + 256, acc);
            }

            reduce_splits(acc, glds, rb, quad, l15, ks);

            float hv0, hv1;
            cell2(glds, n1, u, bi, bf, bg, bo, cr0, cr1, hv0, hv1);
            store_h_slot(hst, h0b + (size_t)(t + 1) * SLOT, s, tid, n1, u, hv0, hv1);

            __syncthreads();   // drains the agent stores (vmcnt) per wave
            if (tid == 0) {
                __hip_atomic_store(f0a + (s << 2), (unsigned)(t + 1),
                                   __ATOMIC_RELAXED, __HIP_MEMORY_SCOPE_AGENT);
                __hip_atomic_store(f0b + (s << 2), (unsigned)(t + 1),
                                   __ATOMIC_RELAXED, __HIP_MEMORY_SCOPE_AGENT);
            }
        }
    } else {
        v8f16 D0[CHUNK], D1[CHUNK];
        for (int t = 0; t < TSTEPS; ++t) {
            // ---- wait for l0 output h0-out[t] (normally already set) ----
            {
                if (tid < 128) {
                    const unsigned* fp = f0b + (tid << 2);
                    unsigned need = (unsigned)(t + 1);
                    while (ld_cnt(fp) < need) __builtin_amdgcn_s_sleep(2);
                }
                __syncthreads();
            }

            v4f32 acc[2][2] = {};
            const f16* qp = h0b + (size_t)(t + 1) * SLOT + jrow;   // layer-0 out (ready)
            const f16* pp = h1b + (size_t)t * SLOT + jrow;         // own recurrence

            // issue Q loads; they fly while we poll our own recurrence flag
            load_sm(qp, 0,     A0, A1);
            load_sm(qp, 32768, C0, C1);
            __builtin_amdgcn_sched_barrier(0);

            if (t > 0) {
                if (tid < 128) {
                    const unsigned* fp = f1 + (tid << 2);
                    unsigned need = (unsigned)t;
                    while (ld_cnt(fp) < need) __builtin_amdgcn_s_sleep(2);
                }
            }
            __syncthreads();

            load_sm(pp, 0, D0, D1);                                // P0
            __builtin_amdgcn_sched_barrier(0);
            mfma_chunk(A0, A1, wlds, l15, kq, kslc,       acc);    // Q0
            load_sm(pp, 32768, A0, A1);                            // P1 (reuse A)
            __builtin_amdgcn_sched_barrier(0);
            mfma_chunk(C0, C1, wlds, l15, kq, kslc + 256, acc);    // Q1
            mfma_chunk(D0, D1, wlds, l15, kq, 1024 + kslc,       acc);   // P0
            mfma_chunk(A0, A1, wlds, l15, kq, 1024 + kslc + 256, acc);   // P1

            reduce_splits(acc, glds, rb, quad, l15, ks);

            float hv0, hv1;
            cell2(glds, n1, u, bi, bf, bg, bo, cr0, cr1, hv0, hv1);
            if (t < TSTEPS - 1) {
                store_h_slot(hst, h1b + (size_t)(t + 1) * SLOT, s, tid, n1, u, hv0, hv1);
                __syncthreads();
                if (tid == 0)
                    __hip_atomic_store(f1 + (s << 2), (unsigned)(t + 1),
                                       __ATOMIC_RELAXED, __HIP_MEMORY_SCOPE_AGENT);
            } else {
                out[(n1 << 10) + jg] = hv0;
                out[((n1 + 64) << 10) + jg] = hv1;
            }
        }
    }
}

extern "C" void kernel_launch(void* const* d_in, const int* in_sizes, int n_in,
                              void* d_out, int out_size, void* d_ws, size_t ws_size,
                              hipStream_t stream) {
    const float* x   = (const float*)d_in[0];
    const float* h0  = (const float*)d_in[1];
    const float* c0  = (const float*)d_in[2];
    const float* Wih = (const float*)d_in[3];
    const float* Whh = (const float*)d_in[4];
    const float* bih = (const float*)d_in[5];
    const float* bhh = (const float*)d_in[6];
    float* out = (float*)d_out;

    char* ws = (char*)d_ws;
    const bool xf16 = (ws_size >= NEED2);

    f16*      wsW  = (f16*)ws;
    float*    wsB  = (float*)(ws + SZ_W);
    f16*      hseq = (f16*)(ws + SZ_W + SZ_B);
    unsigned* bar  = (unsigned*)(ws + SZ_W + SZ_B + SZ_HSEQ);
    f16*      xf   = (f16*)(ws + NEED1);
    int do_xf = xf16 ? 1 : 0;

    lstm_init<<<2048, 256, 0, stream>>>(x, h0, Wih, Whh, bih, bhh,
                                        wsW, wsB, hseq, bar, xf, do_xf);

    void* kargs[] = { (void*)&x, (void*)&xf, (void*)&wsW, (void*)&wsB,
                      (void*)&hseq, (void*)&c0, (void*)&out, (void*)&bar };
    if (xf16) {
        hipLaunchCooperativeKernel((void*)&lstm_main<true>, dim3(256), dim3(512), kargs, 0, stream);
    } else {
        hipLaunchCooperativeKernel((void*)&lstm_main<false>, dim3(256), dim3(512), kargs, 0, stream);
    }
}